// Round 12
// baseline (725.688 us; speedup 1.0000x reference)
//
#include <hip/hip_runtime.h>
#include <stdint.h>

typedef __attribute__((ext_vector_type(8))) short short8;
typedef __attribute__((ext_vector_type(4))) float f32x4;

constexpr int      BATCH    = 524288;
constexpr int      ARRAY_SZ = 262144;
constexpr uint64_t PRIME    = 2038074743ull;
constexpr uint32_t RANGE    = 262137u;          // ARRAY_SZ - 8 + 1
constexpr int      NMT      = BATCH / 16;       // 32768 M-tiles of 16 elements
constexpr int      TSTRIDE  = 136;              // T row stride (shorts), padded
// Rigorous sign-certainty bound (rounds 10-11, absmax 0.0): flagged entries are
// recomputed with the sequential fmaf chain proven bit-exact in rounds 1-11.
constexpr float    EPS      = 8e-5f;

__global__ __launch_bounds__(256, 4)
void lma_mfma3(const float* __restrict__ x,
               const float* __restrict__ hw,
               const float* __restrict__ lsh,
               const void* __restrict__ rnd_raw,
               float* __restrict__ out_idx,   // B*128 floats (idx as f32)
               float* __restrict__ out_val)   // B*64 floats
{
    // T[n][i]: lsh transposed to bf16 (exact: values in {-1,0,1}); padded row
    // stride 136 shorts. ONLY LDS use (34816 B -> 4 blocks/CU).
    __shared__ unsigned short T[128 * TSTRIDE];

    const int tid  = threadIdx.x;
    const int lane = tid & 63;
    const int wid  = __builtin_amdgcn_readfirstlane(tid >> 6);

    // --- hash constants: detect int64 vs int32 layout of random_numbers ---
    uint64_t HA, HB, HC0;
    {
        const uint64_t first8 = *reinterpret_cast<const uint64_t*>(rnd_raw);
        if (first8 == PRIME) {
            const long long* r64 = reinterpret_cast<const long long*>(rnd_raw);
            HA = (uint64_t)r64[1]; HB = (uint64_t)r64[2]; HC0 = (uint64_t)r64[3];
        } else {
            const int* r32 = reinterpret_cast<const int*>(rnd_raw);
            HA  = (uint64_t)(uint32_t)r32[1];
            HB  = (uint64_t)(uint32_t)r32[2];
            HC0 = (uint64_t)(uint32_t)r32[3];
        }
    }

    // --- stage T = bf16(lsh)^T (one-time; bf16 of +-1/0 = high 16 bits) ---
    for (int it = 0; it < 16; ++it) {
        const int flat4 = it * 256 + tid;            // 0..4095
        const int i  = flat4 >> 5;                   // input dim 0..127
        const int n4 = (flat4 & 31) << 2;            // output col base
        const f32x4 v = *reinterpret_cast<const f32x4*>(lsh + i * 128 + n4);
#pragma unroll
        for (int d = 0; d < 4; ++d)
            T[(n4 + d) * TSTRIDE + i] =
                (unsigned short)(__float_as_uint(v[d]) >> 16);
    }
    __syncthreads();   // only barrier; T is read-only afterwards

    const int r     = lane & 15;        // A/B fragment row (x row, T col)
    const int g     = lane >> 4;        // k-group
    const int rj    = lane & 7;         // bit position within chunk byte
    const int hf    = (lane >> 3) & 1;  // which half of the 16-col block
    const int base4 = (lane >> 4) * 4;  // first of this lane's 4 task rows
    const int cc    = rj * 2 + hf;      // this lane's global chunk 0..15
    const int rep   = cc >> 3;
    const int cch   = cc & 7;           // chunk id within rep
    const uint64_t hcc    = HB * (uint64_t)cch + HC0;
    const uint32_t repoff = rep ? (uint32_t)ARRAY_SZ : 0u;

    for (int mt = blockIdx.x * 4 + wid; mt < NMT; mt += 8192) {
        const int Mb = mt * 16;
        const float* xb = x + (size_t)Mb * 128;

        f32x4 acc[8];
#pragma unroll
        for (int n8 = 0; n8 < 8; ++n8) acc[n8] = (f32x4)(0.0f);
        float asum = 0.0f;

        // ---- phase 1: exact 3-way split MFMA (identical to rounds 10-11) ----
#pragma unroll
        for (int ks = 0; ks < 4; ++ks) {
            const float* xp = xb + r * 128 + ks * 32 + g * 8;
            const f32x4 xa = *reinterpret_cast<const f32x4*>(xp);
            const f32x4 xc = *reinterpret_cast<const f32x4*>(xp + 4);
            float xs[8] = {xa[0], xa[1], xa[2], xa[3], xc[0], xc[1], xc[2], xc[3]};
#pragma unroll
            for (int j = 0; j < 8; ++j) asum += fabsf(xs[j]);

            union { uint32_t u[4]; short8 v; } Ahi, Ami, Alo;
#pragma unroll
            for (int p = 0; p < 4; ++p) {
                const uint32_t b0 = __float_as_uint(xs[2 * p]);
                const uint32_t b1 = __float_as_uint(xs[2 * p + 1]);
                const uint32_t h0 = b0 & 0xFFFF0000u, h1 = b1 & 0xFFFF0000u;
                const float    t0 = xs[2 * p] - __uint_as_float(h0);
                const float    t1 = xs[2 * p + 1] - __uint_as_float(h1);
                const uint32_t m0 = __float_as_uint(t0) & 0xFFFF0000u;
                const uint32_t m1 = __float_as_uint(t1) & 0xFFFF0000u;
                const float    u0 = t0 - __uint_as_float(m0);
                const float    u1 = t1 - __uint_as_float(m1);
                const uint32_t l0 = __float_as_uint(u0) & 0xFFFF0000u;
                const uint32_t l1 = __float_as_uint(u1) & 0xFFFF0000u;
                Ahi.u[p] = h1 | (h0 >> 16);
                Ami.u[p] = m1 | (m0 >> 16);
                Alo.u[p] = l1 | (l0 >> 16);
            }
#pragma unroll
            for (int n8 = 0; n8 < 8; ++n8) {
                const short8 bf = *reinterpret_cast<const short8*>(
                    &T[(n8 * 16 + r) * TSTRIDE + (ks * 4 + g) * 8]);
                acc[n8] = __builtin_amdgcn_mfma_f32_16x16x32_bf16(Ahi.v, bf, acc[n8], 0, 0, 0);
                acc[n8] = __builtin_amdgcn_mfma_f32_16x16x32_bf16(Ami.v, bf, acc[n8], 0, 0, 0);
                acc[n8] = __builtin_amdgcn_mfma_f32_16x16x32_bf16(Alo.v, bf, acc[n8], 0, 0, 0);
            }
        }

        // row-|x| sums: reduce over k-groups; lane l&15 = r holds row r's sum
        asum += __shfl_xor(asum, 16);
        asum += __shfl_xor(asum, 32);
        float bnd[4];
#pragma unroll
        for (int reg = 0; reg < 4; ++reg)
            bnd[reg] = __shfl(asum, base4 + reg) * EPS;

        // ---- in-register srp/flag assembly: 3-hop OR-reduce per n8 block ----
        // D layout (m89): lane holds col n8*16+r, rows base4+reg. Bit j of the
        // chunk byte = col&7 = rj. After xor(1,2,4)-OR, each lane has complete
        // bytes for its 4 rows x its own chunk cc (select n8 == rj).
        uint32_t wsrp = 0, wflg = 0;
#pragma unroll
        for (int n8 = 0; n8 < 8; ++n8) {
            uint32_t ws = 0, wf = 0;
#pragma unroll
            for (int reg = 0; reg < 4; ++reg) {
                ws |= (acc[n8][reg] > 0.0f ? 1u : 0u) << (8 * reg + rj);
                wf |= (fabsf(acc[n8][reg]) <= bnd[reg] ? 1u : 0u) << (8 * reg + rj);
            }
            ws |= __shfl_xor(ws, 1); ws |= __shfl_xor(ws, 2); ws |= __shfl_xor(ws, 4);
            wf |= __shfl_xor(wf, 1); wf |= __shfl_xor(wf, 2); wf |= __shfl_xor(wf, 4);
            if (n8 == rj) { wsrp = ws; wflg = wf; }   // per-lane select (cndmask)
        }

        // ---- phase 2: 4 tasks per lane (rows base4+reg, chunk cc) ----
#pragma unroll
        for (int reg = 0; reg < 4; ++reg) {
            const int    m  = base4 + reg;
            const size_t eg = (size_t)(Mb + m);
            uint32_t srp = (wsrp >> (8 * reg)) & 0xFFu;
            const uint32_t flg = (wflg >> (8 * reg)) & 0xFFu;
            if (flg) {  // rare exact fallback: sequential fmaf, i = 0..127
                const float* xr = x + eg * 128;
                for (uint32_t fb = flg; fb; fb &= fb - 1) {
                    const int j = __builtin_ctz(fb);
                    const int k = cc * 8 + j;
                    float s = 0.0f;
#pragma unroll
                    for (int i8 = 0; i8 < 16; ++i8) {
                        const uint4 tb = *reinterpret_cast<const uint4*>(
                            &T[k * TSTRIDE + i8 * 8]);
                        const f32x4 xA = *reinterpret_cast<const f32x4*>(xr + i8 * 8);
                        const f32x4 xB = *reinterpret_cast<const f32x4*>(xr + i8 * 8 + 4);
                        const uint32_t tu[4] = {tb.x, tb.y, tb.z, tb.w};
                        s = __builtin_fmaf(xA[0], __uint_as_float(tu[0] << 16), s);
                        s = __builtin_fmaf(xA[1], __uint_as_float(tu[0] & 0xFFFF0000u), s);
                        s = __builtin_fmaf(xA[2], __uint_as_float(tu[1] << 16), s);
                        s = __builtin_fmaf(xA[3], __uint_as_float(tu[1] & 0xFFFF0000u), s);
                        s = __builtin_fmaf(xB[0], __uint_as_float(tu[2] << 16), s);
                        s = __builtin_fmaf(xB[1], __uint_as_float(tu[2] & 0xFFFF0000u), s);
                        s = __builtin_fmaf(xB[2], __uint_as_float(tu[3] << 16), s);
                        s = __builtin_fmaf(xB[3], __uint_as_float(tu[3] & 0xFFFF0000u), s);
                    }
                    srp = (srp & ~(1u << j)) | ((s > 0.0f) ? (1u << j) : 0u);
                }
            }
            const uint64_t hh  = (HA * (uint64_t)srp + hcc) % PRIME;
            const uint32_t loc = (uint32_t)hh % RANGE + repoff;

            const float f0 = (float)loc;
            float* oi = out_idx + eg * 128 + cc * 8;
            *reinterpret_cast<f32x4*>(oi)     = (f32x4){f0, f0 + 1.f, f0 + 2.f, f0 + 3.f};
            *reinterpret_cast<f32x4*>(oi + 4) = (f32x4){f0 + 4.f, f0 + 5.f, f0 + 6.f, f0 + 7.f};

            float wv[8];
#pragma unroll
            for (int j = 0; j < 8; ++j) wv[j] = hw[loc + j];

            // rep partner (chunk cc^8) sits at lane^4: one shuffle averages
            float v[8];
#pragma unroll
            for (int j = 0; j < 8; ++j)
                v[j] = (wv[j] + __shfl_xor(wv[j], 4)) * 0.5f;

            if (rep == 0) {   // chunks 0..7 store the averaged values
                float* ov = out_val + eg * 64 + cc * 8;
                *reinterpret_cast<f32x4*>(ov)     = (f32x4){v[0], v[1], v[2], v[3]};
                *reinterpret_cast<f32x4*>(ov + 4) = (f32x4){v[4], v[5], v[6], v[7]};
            }
        }
    }
}

extern "C" void kernel_launch(void* const* d_in, const int* in_sizes, int n_in,
                              void* d_out, int out_size, void* d_ws, size_t ws_size,
                              hipStream_t stream) {
    const float* x   = (const float*)d_in[0];
    const float* hw  = (const float*)d_in[1];
    const float* lsh = (const float*)d_in[2];
    const void*  rnd = (const void*)d_in[3];

    float* out_idx = (float*)d_out;
    float* out_val = out_idx + (size_t)BATCH * 128;

    lma_mfma3<<<2048, 256, 0, stream>>>(x, hw, lsh, rnd, out_idx, out_val);
}

// Round 13
// 384.676 us; speedup vs baseline: 1.8865x; 1.8865x over previous
//
#include <hip/hip_runtime.h>
#include <stdint.h>

typedef __attribute__((ext_vector_type(8))) short short8;
typedef __attribute__((ext_vector_type(4))) float f32x4;

constexpr int      BATCH    = 524288;
constexpr int      ARRAY_SZ = 262144;
constexpr uint64_t PRIME    = 2038074743ull;
constexpr uint32_t RANGE    = 262137u;          // ARRAY_SZ - 8 + 1
constexpr int      NMT      = BATCH / 16;       // 32768 M-tiles of 16 elements
constexpr int      TSTRIDE  = 136;              // T row stride (shorts), padded
// Rigorous sign-certainty bound (rounds 10-12, absmax 0.0): flagged entries are
// recomputed with the sequential fmaf chain proven bit-exact in rounds 1-12.
constexpr float    EPS      = 8e-5f;

// NOTE: (256,2) NOT (256,4) — the min-waves bound caps the register allocator
// (cap = 512/waves); this structure needs ~140 VGPR. Round 12's (256,4) forced
// cap 128 -> full spill (FETCH 987 MB, 726 us). Round 10 proved (256,2) fits.
__global__ __launch_bounds__(256, 2)
void lma_mfma4(const float* __restrict__ x,
               const float* __restrict__ hw,
               const float* __restrict__ lsh,
               const void* __restrict__ rnd_raw,
               float* __restrict__ out_idx,   // B*128 floats (idx as f32)
               float* __restrict__ out_val)   // B*64 floats
{
    // T[n][i]: lsh transposed to bf16 (exact: values in {-1,0,1}); padded row
    // stride 136 shorts. ONLY LDS use (34816 B -> LDS allows 4 blocks/CU).
    __shared__ unsigned short T[128 * TSTRIDE];

    const int tid  = threadIdx.x;
    const int lane = tid & 63;
    const int wid  = __builtin_amdgcn_readfirstlane(tid >> 6);

    // --- hash constants: detect int64 vs int32 layout of random_numbers ---
    uint64_t HA, HB, HC0;
    {
        const uint64_t first8 = *reinterpret_cast<const uint64_t*>(rnd_raw);
        if (first8 == PRIME) {
            const long long* r64 = reinterpret_cast<const long long*>(rnd_raw);
            HA = (uint64_t)r64[1]; HB = (uint64_t)r64[2]; HC0 = (uint64_t)r64[3];
        } else {
            const int* r32 = reinterpret_cast<const int*>(rnd_raw);
            HA  = (uint64_t)(uint32_t)r32[1];
            HB  = (uint64_t)(uint32_t)r32[2];
            HC0 = (uint64_t)(uint32_t)r32[3];
        }
    }

    // --- stage T = bf16(lsh)^T (one-time; bf16 of +-1/0 = high 16 bits) ---
    for (int it = 0; it < 16; ++it) {
        const int flat4 = it * 256 + tid;            // 0..4095
        const int i  = flat4 >> 5;                   // input dim 0..127
        const int n4 = (flat4 & 31) << 2;            // output col base
        const f32x4 v = *reinterpret_cast<const f32x4*>(lsh + i * 128 + n4);
#pragma unroll
        for (int d = 0; d < 4; ++d)
            T[(n4 + d) * TSTRIDE + i] =
                (unsigned short)(__float_as_uint(v[d]) >> 16);
    }
    __syncthreads();   // only barrier; T is read-only afterwards

    const int r     = lane & 15;        // A/B fragment row (x row, T col)
    const int g     = lane >> 4;        // k-group
    const int rj    = lane & 7;         // bit position within chunk byte
    const int hf    = (lane >> 3) & 1;  // which half of the 16-col block
    const int base4 = (lane >> 4) * 4;  // first of this lane's 4 task rows
    const int cc    = rj * 2 + hf;      // this lane's global chunk 0..15
    const int rep   = cc >> 3;
    const int cch   = cc & 7;           // chunk id within rep
    const uint64_t hcc    = HB * (uint64_t)cch + HC0;
    const uint32_t repoff = rep ? (uint32_t)ARRAY_SZ : 0u;

    for (int mt = blockIdx.x * 4 + wid; mt < NMT; mt += 8192) {
        const int Mb = mt * 16;
        const float* xb = x + (size_t)Mb * 128;

        f32x4 acc[8];
#pragma unroll
        for (int n8 = 0; n8 < 8; ++n8) acc[n8] = (f32x4)(0.0f);
        float asum = 0.0f;

        // ---- phase 1: exact 3-way split MFMA (identical to rounds 10-12) ----
#pragma unroll
        for (int ks = 0; ks < 4; ++ks) {
            const float* xp = xb + r * 128 + ks * 32 + g * 8;
            const f32x4 xa = *reinterpret_cast<const f32x4*>(xp);
            const f32x4 xc = *reinterpret_cast<const f32x4*>(xp + 4);
            float xs[8] = {xa[0], xa[1], xa[2], xa[3], xc[0], xc[1], xc[2], xc[3]};
#pragma unroll
            for (int j = 0; j < 8; ++j) asum += fabsf(xs[j]);

            union { uint32_t u[4]; short8 v; } Ahi, Ami, Alo;
#pragma unroll
            for (int p = 0; p < 4; ++p) {
                const uint32_t b0 = __float_as_uint(xs[2 * p]);
                const uint32_t b1 = __float_as_uint(xs[2 * p + 1]);
                const uint32_t h0 = b0 & 0xFFFF0000u, h1 = b1 & 0xFFFF0000u;
                const float    t0 = xs[2 * p] - __uint_as_float(h0);
                const float    t1 = xs[2 * p + 1] - __uint_as_float(h1);
                const uint32_t m0 = __float_as_uint(t0) & 0xFFFF0000u;
                const uint32_t m1 = __float_as_uint(t1) & 0xFFFF0000u;
                const float    u0 = t0 - __uint_as_float(m0);
                const float    u1 = t1 - __uint_as_float(m1);
                const uint32_t l0 = __float_as_uint(u0) & 0xFFFF0000u;
                const uint32_t l1 = __float_as_uint(u1) & 0xFFFF0000u;
                Ahi.u[p] = h1 | (h0 >> 16);
                Ami.u[p] = m1 | (m0 >> 16);
                Alo.u[p] = l1 | (l0 >> 16);
            }
#pragma unroll
            for (int n8 = 0; n8 < 8; ++n8) {
                const short8 bf = *reinterpret_cast<const short8*>(
                    &T[(n8 * 16 + r) * TSTRIDE + (ks * 4 + g) * 8]);
                acc[n8] = __builtin_amdgcn_mfma_f32_16x16x32_bf16(Ahi.v, bf, acc[n8], 0, 0, 0);
                acc[n8] = __builtin_amdgcn_mfma_f32_16x16x32_bf16(Ami.v, bf, acc[n8], 0, 0, 0);
                acc[n8] = __builtin_amdgcn_mfma_f32_16x16x32_bf16(Alo.v, bf, acc[n8], 0, 0, 0);
            }
        }

        // row-|x| sums: reduce over k-groups; lane l&15 = r holds row r's sum
        asum += __shfl_xor(asum, 16);
        asum += __shfl_xor(asum, 32);
        float bnd[4];
#pragma unroll
        for (int reg = 0; reg < 4; ++reg)
            bnd[reg] = __shfl(asum, base4 + reg) * EPS;

        // ---- in-register srp/flag assembly: 3-hop OR-reduce per n8 block ----
        // D layout (m89): lane holds col n8*16+r, rows base4+reg. Bit j of the
        // chunk byte = col&7 = rj. After xor(1,2,4)-OR, each lane has complete
        // bytes for its 4 rows x its own chunk cc (select n8 == rj).
        uint32_t wsrp = 0, wflg = 0;
#pragma unroll
        for (int n8 = 0; n8 < 8; ++n8) {
            uint32_t ws = 0, wf = 0;
#pragma unroll
            for (int reg = 0; reg < 4; ++reg) {
                ws |= (acc[n8][reg] > 0.0f ? 1u : 0u) << (8 * reg + rj);
                wf |= (fabsf(acc[n8][reg]) <= bnd[reg] ? 1u : 0u) << (8 * reg + rj);
            }
            ws |= __shfl_xor(ws, 1); ws |= __shfl_xor(ws, 2); ws |= __shfl_xor(ws, 4);
            wf |= __shfl_xor(wf, 1); wf |= __shfl_xor(wf, 2); wf |= __shfl_xor(wf, 4);
            if (n8 == rj) { wsrp = ws; wflg = wf; }   // per-lane select (cndmask)
        }

        // ---- phase 2: 4 tasks per lane (rows base4+reg, chunk cc) ----
#pragma unroll
        for (int reg = 0; reg < 4; ++reg) {
            const int    m  = base4 + reg;
            const size_t eg = (size_t)(Mb + m);
            uint32_t srp = (wsrp >> (8 * reg)) & 0xFFu;
            const uint32_t flg = (wflg >> (8 * reg)) & 0xFFu;
            if (flg) {  // rare exact fallback: sequential fmaf, i = 0..127
                const float* xr = x + eg * 128;
                for (uint32_t fb = flg; fb; fb &= fb - 1) {
                    const int j = __builtin_ctz(fb);
                    const int k = cc * 8 + j;
                    float s = 0.0f;
#pragma unroll
                    for (int i8 = 0; i8 < 16; ++i8) {
                        const uint4 tb = *reinterpret_cast<const uint4*>(
                            &T[k * TSTRIDE + i8 * 8]);
                        const f32x4 xA = *reinterpret_cast<const f32x4*>(xr + i8 * 8);
                        const f32x4 xB = *reinterpret_cast<const f32x4*>(xr + i8 * 8 + 4);
                        const uint32_t tu[4] = {tb.x, tb.y, tb.z, tb.w};
                        s = __builtin_fmaf(xA[0], __uint_as_float(tu[0] << 16), s);
                        s = __builtin_fmaf(xA[1], __uint_as_float(tu[0] & 0xFFFF0000u), s);
                        s = __builtin_fmaf(xA[2], __uint_as_float(tu[1] << 16), s);
                        s = __builtin_fmaf(xA[3], __uint_as_float(tu[1] & 0xFFFF0000u), s);
                        s = __builtin_fmaf(xB[0], __uint_as_float(tu[2] << 16), s);
                        s = __builtin_fmaf(xB[1], __uint_as_float(tu[2] & 0xFFFF0000u), s);
                        s = __builtin_fmaf(xB[2], __uint_as_float(tu[3] << 16), s);
                        s = __builtin_fmaf(xB[3], __uint_as_float(tu[3] & 0xFFFF0000u), s);
                    }
                    srp = (srp & ~(1u << j)) | ((s > 0.0f) ? (1u << j) : 0u);
                }
            }
            const uint64_t hh  = (HA * (uint64_t)srp + hcc) % PRIME;
            const uint32_t loc = (uint32_t)hh % RANGE + repoff;

            const float f0 = (float)loc;
            float* oi = out_idx + eg * 128 + cc * 8;
            *reinterpret_cast<f32x4*>(oi)     = (f32x4){f0, f0 + 1.f, f0 + 2.f, f0 + 3.f};
            *reinterpret_cast<f32x4*>(oi + 4) = (f32x4){f0 + 4.f, f0 + 5.f, f0 + 6.f, f0 + 7.f};

            float wv[8];
#pragma unroll
            for (int j = 0; j < 8; ++j) wv[j] = hw[loc + j];

            // rep partner (chunk cc^8) sits at lane^4: one shuffle averages
            float v[8];
#pragma unroll
            for (int j = 0; j < 8; ++j)
                v[j] = (wv[j] + __shfl_xor(wv[j], 4)) * 0.5f;

            if (rep == 0) {   // chunks 0..7 store the averaged values
                float* ov = out_val + eg * 64 + cc * 8;
                *reinterpret_cast<f32x4*>(ov)     = (f32x4){v[0], v[1], v[2], v[3]};
                *reinterpret_cast<f32x4*>(ov + 4) = (f32x4){v[4], v[5], v[6], v[7]};
            }
        }
    }
}

extern "C" void kernel_launch(void* const* d_in, const int* in_sizes, int n_in,
                              void* d_out, int out_size, void* d_ws, size_t ws_size,
                              hipStream_t stream) {
    const float* x   = (const float*)d_in[0];
    const float* hw  = (const float*)d_in[1];
    const float* lsh = (const float*)d_in[2];
    const void*  rnd = (const void*)d_in[3];

    float* out_idx = (float*)d_out;
    float* out_val = out_idx + (size_t)BATCH * 128;

    lma_mfma4<<<2048, 256, 0, stream>>>(x, hw, lsh, rnd, out_idx, out_val);
}

// Round 14
// 294.017 us; speedup vs baseline: 2.4682x; 1.3083x over previous
//
#include <hip/hip_runtime.h>
#include <stdint.h>

typedef __attribute__((ext_vector_type(8))) short short8;
typedef __attribute__((ext_vector_type(4))) float f32x4;

constexpr int      BATCH    = 524288;
constexpr int      ARRAY_SZ = 262144;
constexpr uint64_t PRIME    = 2038074743ull;
constexpr uint32_t RANGE    = 262137u;          // ARRAY_SZ - 8 + 1
constexpr int      NMT      = BATCH / 16;       // 32768 M-tiles of 16 elements
constexpr int      PSTRIDE  = 68;               // pw row stride (dwords), padded
// Rigorous sign-certainty bound (rounds 10-13, absmax 0.0): flagged entries are
// recomputed with the sequential fmaf chain proven bit-exact in rounds 1-13.
constexpr float    EPS      = 8e-5f;

__global__ __launch_bounds__(256, 2)
void lma_mfma5(const float* __restrict__ x,
               const float* __restrict__ hw,
               const float* __restrict__ lsh,
               const void* __restrict__ rnd_raw,
               float* __restrict__ out_idx,   // B*128 floats (idx as f32)
               float* __restrict__ out_val)   // B*64 floats
{
    // T[n][i]: lsh^T as bf16 (exact: {-1,0,1}); 16B-unit XOR swizzle (r10,
    // proven): conflict at the b128 floor only. 32768 B.
    __shared__ unsigned short T[128 * 128];
    // pw: per-WAVE transpose buffer for one rep-half (no block barriers).
    __shared__ float pw[4][16 * PSTRIDE];            // 17408 B

    const int tid  = threadIdx.x;
    const int lane = tid & 63;
    const int wid  = __builtin_amdgcn_readfirstlane(tid >> 6);

    // --- hash constants: detect int64 vs int32 layout of random_numbers ---
    uint64_t HA, HB, HC0;
    {
        const uint64_t first8 = *reinterpret_cast<const uint64_t*>(rnd_raw);
        if (first8 == PRIME) {
            const long long* r64 = reinterpret_cast<const long long*>(rnd_raw);
            HA = (uint64_t)r64[1]; HB = (uint64_t)r64[2]; HC0 = (uint64_t)r64[3];
        } else {
            const int* r32 = reinterpret_cast<const int*>(rnd_raw);
            HA  = (uint64_t)(uint32_t)r32[1];
            HB  = (uint64_t)(uint32_t)r32[2];
            HC0 = (uint64_t)(uint32_t)r32[3];
        }
    }

    // --- stage T = bf16(lsh)^T, XOR-swizzled (one-time) ---
    for (int it = 0; it < 16; ++it) {
        const int flat4 = it * 256 + tid;            // 0..4095
        const int i  = flat4 >> 5;                   // input dim 0..127
        const int n4 = (flat4 & 31) << 2;            // output col base
        const f32x4 v = *reinterpret_cast<const f32x4*>(lsh + i * 128 + n4);
#pragma unroll
        for (int d = 0; d < 4; ++d) {
            const int n = n4 + d;
            T[n * 128 + (((i >> 3) ^ (n & 15)) << 3) + (i & 7)] =
                (unsigned short)(__float_as_uint(v[d]) >> 16);
        }
    }
    __syncthreads();   // only block barrier; T read-only afterwards

    const int r  = lane & 15;         // A/B fragment row (x row, T col)
    const int g  = lane >> 4;         // k-group
    const int e  = lane >> 2;         // phase-2 element (0..15)
    const int c4 = lane & 3;          // phase-2 chunk slot

    for (int mt = blockIdx.x * 4 + wid; mt < NMT; mt += 8192) {
        const int Mb = mt * 16;
        const float* xb = x + (size_t)Mb * 128;

        f32x4 acc[8];
#pragma unroll
        for (int n8 = 0; n8 < 8; ++n8) acc[n8] = (f32x4)(0.0f);
        float asum = 0.0f;

        // ---- phase 1: exact 3-way split MFMA (identical to rounds 10-13) ----
#pragma unroll
        for (int ks = 0; ks < 4; ++ks) {
            const float* xp = xb + r * 128 + ks * 32 + g * 8;
            const f32x4 xa = *reinterpret_cast<const f32x4*>(xp);
            const f32x4 xc = *reinterpret_cast<const f32x4*>(xp + 4);
            float xs[8] = {xa[0], xa[1], xa[2], xa[3], xc[0], xc[1], xc[2], xc[3]};
#pragma unroll
            for (int j = 0; j < 8; ++j) asum += fabsf(xs[j]);

            union { uint32_t u[4]; short8 v; } Ahi, Ami, Alo;
#pragma unroll
            for (int p = 0; p < 4; ++p) {
                const uint32_t b0 = __float_as_uint(xs[2 * p]);
                const uint32_t b1 = __float_as_uint(xs[2 * p + 1]);
                const uint32_t h0 = b0 & 0xFFFF0000u, h1 = b1 & 0xFFFF0000u;
                const float    t0 = xs[2 * p] - __uint_as_float(h0);
                const float    t1 = xs[2 * p + 1] - __uint_as_float(h1);
                const uint32_t m0 = __float_as_uint(t0) & 0xFFFF0000u;
                const uint32_t m1 = __float_as_uint(t1) & 0xFFFF0000u;
                const float    u0 = t0 - __uint_as_float(m0);
                const float    u1 = t1 - __uint_as_float(m1);
                const uint32_t l0 = __float_as_uint(u0) & 0xFFFF0000u;
                const uint32_t l1 = __float_as_uint(u1) & 0xFFFF0000u;
                Ahi.u[p] = h1 | (h0 >> 16);
                Ami.u[p] = m1 | (m0 >> 16);
                Alo.u[p] = l1 | (l0 >> 16);
            }
#pragma unroll
            for (int n8 = 0; n8 < 8; ++n8) {
                const short8 bf = *reinterpret_cast<const short8*>(
                    &T[(n8 * 16 + r) * 128 + (((ks * 4 + g) ^ r) << 3)]);
                acc[n8] = __builtin_amdgcn_mfma_f32_16x16x32_bf16(Ahi.v, bf, acc[n8], 0, 0, 0);
                acc[n8] = __builtin_amdgcn_mfma_f32_16x16x32_bf16(Ami.v, bf, acc[n8], 0, 0, 0);
                acc[n8] = __builtin_amdgcn_mfma_f32_16x16x32_bf16(Alo.v, bf, acc[n8], 0, 0, 0);
            }
        }

        // row-|x| sums over k-groups; each lane picks its element's bound
        asum += __shfl_xor(asum, 16);
        asum += __shfl_xor(asum, 32);
        const float bnd = __shfl(asum, e) * EPS;

        const size_t eg = (size_t)(Mb + e);
        float wkeep[2][8];

        // ---- phase 2 per rep-half: wave-private transpose, no barriers ----
#pragma unroll
        for (int hh = 0; hh < 2; ++hh) {
            // D layout (m89): lane holds col n8*16+r, rows g*4+reg
#pragma unroll
            for (int n8h = 0; n8h < 4; ++n8h)
#pragma unroll
                for (int reg = 0; reg < 4; ++reg)
                    pw[wid][(g * 4 + reg) * PSTRIDE + n8h * 16 + r] =
                        acc[hh * 4 + n8h][reg];
            // wave-local: drain DS writes before dependent reads
            asm volatile("s_waitcnt lgkmcnt(0)" ::: "memory");

#pragma unroll
            for (int m = 0; m < 2; ++m) {
                const int ccl = c4 + 4 * m;          // chunk id within rep
                const f32x4 pa = *reinterpret_cast<const f32x4*>(
                    &pw[wid][e * PSTRIDE + ccl * 8]);
                const f32x4 pb = *reinterpret_cast<const f32x4*>(
                    &pw[wid][e * PSTRIDE + ccl * 8 + 4]);
                const float p[8] = {pa[0], pa[1], pa[2], pa[3],
                                    pb[0], pb[1], pb[2], pb[3]};
                uint32_t srp = 0, flg = 0;
#pragma unroll
                for (int j = 0; j < 8; ++j) {
                    srp |= (p[j] > 0.0f) ? (1u << j) : 0u;
                    flg |= (fabsf(p[j]) <= bnd) ? (1u << j) : 0u;
                }
                if (flg) {  // rare exact fallback: sequential fmaf, i = 0..127
                    const float* xr = x + eg * 128;
                    for (uint32_t fb = flg; fb; fb &= fb - 1) {
                        const int j = __builtin_ctz(fb);
                        const int k = hh * 64 + ccl * 8 + j;
                        float s = 0.0f;
#pragma unroll 4
                        for (int i8 = 0; i8 < 16; ++i8) {
                            const uint4 tb = *reinterpret_cast<const uint4*>(
                                &T[k * 128 + ((i8 ^ (k & 15)) << 3)]);
                            const f32x4 xA = *reinterpret_cast<const f32x4*>(xr + i8 * 8);
                            const f32x4 xB = *reinterpret_cast<const f32x4*>(xr + i8 * 8 + 4);
                            const uint32_t tu[4] = {tb.x, tb.y, tb.z, tb.w};
                            s = __builtin_fmaf(xA[0], __uint_as_float(tu[0] << 16), s);
                            s = __builtin_fmaf(xA[1], __uint_as_float(tu[0] & 0xFFFF0000u), s);
                            s = __builtin_fmaf(xA[2], __uint_as_float(tu[1] << 16), s);
                            s = __builtin_fmaf(xA[3], __uint_as_float(tu[1] & 0xFFFF0000u), s);
                            s = __builtin_fmaf(xB[0], __uint_as_float(tu[2] << 16), s);
                            s = __builtin_fmaf(xB[1], __uint_as_float(tu[2] & 0xFFFF0000u), s);
                            s = __builtin_fmaf(xB[2], __uint_as_float(tu[3] << 16), s);
                            s = __builtin_fmaf(xB[3], __uint_as_float(tu[3] & 0xFFFF0000u), s);
                        }
                        srp = (srp & ~(1u << j)) | ((s > 0.0f) ? (1u << j) : 0u);
                    }
                }
                const uint64_t hhash = (HA * (uint64_t)srp + HB * (uint64_t)ccl + HC0) % PRIME;
                const uint32_t loc   = (uint32_t)hhash % RANGE + (hh ? (uint32_t)ARRAY_SZ : 0u);

                const float f0 = (float)loc;
                float* oi = out_idx + eg * 128 + hh * 64 + ccl * 8;
                *reinterpret_cast<f32x4*>(oi)     = (f32x4){f0, f0 + 1.f, f0 + 2.f, f0 + 3.f};
                *reinterpret_cast<f32x4*>(oi + 4) = (f32x4){f0 + 4.f, f0 + 5.f, f0 + 6.f, f0 + 7.f};

                float wv[8];
#pragma unroll
                for (int j = 0; j < 8; ++j) wv[j] = hw[loc + j];
                if (hh == 0) {
#pragma unroll
                    for (int j = 0; j < 8; ++j) wkeep[m][j] = wv[j];
                } else {
                    float* ov = out_val + eg * 64 + ccl * 8;
                    *reinterpret_cast<f32x4*>(ov) =
                        (f32x4){(wkeep[m][0] + wv[0]) * 0.5f, (wkeep[m][1] + wv[1]) * 0.5f,
                                (wkeep[m][2] + wv[2]) * 0.5f, (wkeep[m][3] + wv[3]) * 0.5f};
                    *reinterpret_cast<f32x4*>(ov + 4) =
                        (f32x4){(wkeep[m][4] + wv[4]) * 0.5f, (wkeep[m][5] + wv[5]) * 0.5f,
                                (wkeep[m][6] + wv[6]) * 0.5f, (wkeep[m][7] + wv[7]) * 0.5f};
                }
            }
        }
    }
}

extern "C" void kernel_launch(void* const* d_in, const int* in_sizes, int n_in,
                              void* d_out, int out_size, void* d_ws, size_t ws_size,
                              hipStream_t stream) {
    const float* x   = (const float*)d_in[0];
    const float* hw  = (const float*)d_in[1];
    const float* lsh = (const float*)d_in[2];
    const void*  rnd = (const void*)d_in[3];

    float* out_idx = (float*)d_out;
    float* out_val = out_idx + (size_t)BATCH * 128;

    lma_mfma5<<<2048, 256, 0, stream>>>(x, hw, lsh, rnd, out_idx, out_val);
}

// Round 16
// 279.171 us; speedup vs baseline: 2.5994x; 1.0532x over previous
//
#include <hip/hip_runtime.h>
#include <stdint.h>

typedef __attribute__((ext_vector_type(8))) short short8;
typedef __attribute__((ext_vector_type(4))) float f32x4;

constexpr int      BATCH    = 524288;
constexpr int      ARRAY_SZ = 262144;
constexpr uint64_t PRIME    = 2038074743ull;
constexpr uint32_t RANGE    = 262137u;          // ARRAY_SZ - 8 + 1
constexpr int      NMT      = BATCH / 16;       // 32768 M-tiles of 16 elements
constexpr int      PSTRIDE  = 68;               // pw row stride (dwords): rows are
                                                // 64 cols wide + 4 pad (r15 bug: 33)
// Rigorous sign-certainty bound (rounds 10-14, absmax 0.0): flagged entries are
// recomputed with the sequential fmaf chain proven bit-exact in rounds 1-14.
constexpr float    EPS      = 8e-5f;

__global__ __launch_bounds__(256, 2)
void lma_mfma7(const float* __restrict__ x,
               const float* __restrict__ hw,
               const float* __restrict__ lsh,
               const void* __restrict__ rnd_raw,
               float* __restrict__ out_idx,   // B*128 floats (idx as f32)
               float* __restrict__ out_val)   // B*64 floats
{
    // T[n][i]: lsh^T as bf16 (exact: {-1,0,1}); 16B-unit XOR swizzle (proven
    // r10/r14): conflicts at the b128 structural floor only. 32768 B.
    __shared__ unsigned short T[128 * 128];
    // pw: per-WAVE transpose buffer for one rep-half (two-pass, r14-proven).
    __shared__ float pw[4][16 * PSTRIDE];            // 17408 B -> total 50176 B

    const int tid  = threadIdx.x;
    const int lane = tid & 63;
    const int wid  = __builtin_amdgcn_readfirstlane(tid >> 6);

    // --- hash constants: detect int64 vs int32 layout of random_numbers ---
    uint64_t HA, HB, HC0;
    {
        const uint64_t first8 = *reinterpret_cast<const uint64_t*>(rnd_raw);
        if (first8 == PRIME) {
            const long long* r64 = reinterpret_cast<const long long*>(rnd_raw);
            HA = (uint64_t)r64[1]; HB = (uint64_t)r64[2]; HC0 = (uint64_t)r64[3];
        } else {
            const int* r32 = reinterpret_cast<const int*>(rnd_raw);
            HA  = (uint64_t)(uint32_t)r32[1];
            HB  = (uint64_t)(uint32_t)r32[2];
            HC0 = (uint64_t)(uint32_t)r32[3];
        }
    }

    // --- stage T = bf16(lsh)^T, XOR-swizzled (one-time) ---
    for (int it = 0; it < 16; ++it) {
        const int flat4 = it * 256 + tid;            // 0..4095
        const int i  = flat4 >> 5;                   // input dim 0..127
        const int n4 = (flat4 & 31) << 2;            // output col base
        const f32x4 v = *reinterpret_cast<const f32x4*>(lsh + i * 128 + n4);
#pragma unroll
        for (int d = 0; d < 4; ++d) {
            const int n = n4 + d;
            T[n * 128 + (((i >> 3) ^ (n & 15)) << 3) + (i & 7)] =
                (unsigned short)(__float_as_uint(v[d]) >> 16);
        }
    }
    __syncthreads();   // only block barrier; T read-only afterwards

    const int r  = lane & 15;         // A/B fragment row (x row, T col)
    const int g  = lane >> 4;         // k-group
    const int e  = lane >> 2;         // phase-2 element (0..15)
    const int c4 = lane & 3;          // phase-2 chunk slot

    // --- prologue: prefetch first tile's x fragment into loop-carried regs ---
    const int mt0 = blockIdx.x * 4 + wid;
    f32x4 xp0, xp1, xp2, xp3, xp4, xp5, xp6, xp7;
    {
        const float* xn = x + (size_t)mt0 * 16 * 128 + r * 128 + g * 8;
        xp0 = *reinterpret_cast<const f32x4*>(xn);
        xp1 = *reinterpret_cast<const f32x4*>(xn + 4);
        xp2 = *reinterpret_cast<const f32x4*>(xn + 32);
        xp3 = *reinterpret_cast<const f32x4*>(xn + 36);
        xp4 = *reinterpret_cast<const f32x4*>(xn + 64);
        xp5 = *reinterpret_cast<const f32x4*>(xn + 68);
        xp6 = *reinterpret_cast<const f32x4*>(xn + 96);
        xp7 = *reinterpret_cast<const f32x4*>(xn + 100);
    }

#pragma unroll 1
    for (int mt = mt0; mt < NMT; mt += 8192) {
        const int Mb = mt * 16;

        f32x4 acc[8];
#pragma unroll
        for (int n8 = 0; n8 < 8; ++n8) acc[n8] = (f32x4)(0.0f);
        float asum = 0.0f;

        // ---- phase 1: exact 3-way split MFMA (arith identical to r10-r14);
        //      x comes from the prefetched loop-carried registers ----
#pragma unroll
        for (int ks = 0; ks < 4; ++ks) {
            const f32x4 xa = (ks == 0) ? xp0 : (ks == 1) ? xp2 : (ks == 2) ? xp4 : xp6;
            const f32x4 xc = (ks == 0) ? xp1 : (ks == 1) ? xp3 : (ks == 2) ? xp5 : xp7;
            float xs[8] = {xa[0], xa[1], xa[2], xa[3], xc[0], xc[1], xc[2], xc[3]};
#pragma unroll
            for (int j = 0; j < 8; ++j) asum += fabsf(xs[j]);

            union { uint32_t u[4]; short8 v; } Ahi, Ami, Alo;
#pragma unroll
            for (int p = 0; p < 4; ++p) {
                const uint32_t b0 = __float_as_uint(xs[2 * p]);
                const uint32_t b1 = __float_as_uint(xs[2 * p + 1]);
                const uint32_t h0 = b0 & 0xFFFF0000u, h1 = b1 & 0xFFFF0000u;
                const float    t0 = xs[2 * p] - __uint_as_float(h0);
                const float    t1 = xs[2 * p + 1] - __uint_as_float(h1);
                const uint32_t m0 = __float_as_uint(t0) & 0xFFFF0000u;
                const uint32_t m1 = __float_as_uint(t1) & 0xFFFF0000u;
                const float    u0 = t0 - __uint_as_float(m0);
                const float    u1 = t1 - __uint_as_float(m1);
                const uint32_t l0 = __float_as_uint(u0) & 0xFFFF0000u;
                const uint32_t l1 = __float_as_uint(u1) & 0xFFFF0000u;
                Ahi.u[p] = h1 | (h0 >> 16);
                Ami.u[p] = m1 | (m0 >> 16);
                Alo.u[p] = l1 | (l0 >> 16);
            }
#pragma unroll
            for (int n8 = 0; n8 < 8; ++n8) {
                const short8 bf = *reinterpret_cast<const short8*>(
                    &T[(n8 * 16 + r) * 128 + (((ks * 4 + g) ^ r) << 3)]);
                acc[n8] = __builtin_amdgcn_mfma_f32_16x16x32_bf16(Ahi.v, bf, acc[n8], 0, 0, 0);
                acc[n8] = __builtin_amdgcn_mfma_f32_16x16x32_bf16(Ami.v, bf, acc[n8], 0, 0, 0);
                acc[n8] = __builtin_amdgcn_mfma_f32_16x16x32_bf16(Alo.v, bf, acc[n8], 0, 0, 0);
            }
        }

        // ---- prefetch next tile's x NOW: the whole phase-2 stretch (pw dumps,
        //      two lgkmcnt drains, 32 gathers) hides the HBM latency. Loads
        //      cannot sink past the asm volatile "memory" drains below. ----
        {
            const int mtn = (mt + 8192 < NMT) ? mt + 8192 : mt;
            const float* xn = x + (size_t)mtn * 16 * 128 + r * 128 + g * 8;
            xp0 = *reinterpret_cast<const f32x4*>(xn);
            xp1 = *reinterpret_cast<const f32x4*>(xn + 4);
            xp2 = *reinterpret_cast<const f32x4*>(xn + 32);
            xp3 = *reinterpret_cast<const f32x4*>(xn + 36);
            xp4 = *reinterpret_cast<const f32x4*>(xn + 64);
            xp5 = *reinterpret_cast<const f32x4*>(xn + 68);
            xp6 = *reinterpret_cast<const f32x4*>(xn + 96);
            xp7 = *reinterpret_cast<const f32x4*>(xn + 100);
        }

        // row-|x| sums over k-groups; each lane picks its element's bound
        asum += __shfl_xor(asum, 16);
        asum += __shfl_xor(asum, 32);
        const float bnd = __shfl(asum, e) * EPS;

        const size_t eg = (size_t)(Mb + e);
        float wkeep[2][8];

        // ---- phase 2 per rep-half: wave-private transpose, no barriers ----
#pragma unroll
        for (int hh = 0; hh < 2; ++hh) {
            // D layout (m89): lane holds col n8*16+r, rows g*4+reg
#pragma unroll
            for (int n8h = 0; n8h < 4; ++n8h)
#pragma unroll
                for (int reg = 0; reg < 4; ++reg)
                    pw[wid][(g * 4 + reg) * PSTRIDE + n8h * 16 + r] =
                        acc[hh * 4 + n8h][reg];
            // wave-local: drain DS writes before dependent reads
            asm volatile("s_waitcnt lgkmcnt(0)" ::: "memory");

#pragma unroll
            for (int m = 0; m < 2; ++m) {
                const int ccl = c4 + 4 * m;          // chunk id within rep
                const f32x4 pa = *reinterpret_cast<const f32x4*>(
                    &pw[wid][e * PSTRIDE + ccl * 8]);
                const f32x4 pb = *reinterpret_cast<const f32x4*>(
                    &pw[wid][e * PSTRIDE + ccl * 8 + 4]);
                const float p[8] = {pa[0], pa[1], pa[2], pa[3],
                                    pb[0], pb[1], pb[2], pb[3]};
                uint32_t srp = 0, flg = 0;
#pragma unroll
                for (int j = 0; j < 8; ++j) {
                    srp |= (p[j] > 0.0f) ? (1u << j) : 0u;
                    flg |= (fabsf(p[j]) <= bnd) ? (1u << j) : 0u;
                }
                if (flg) {  // rare exact fallback: sequential fmaf, i = 0..127
                    const float* xr = x + eg * 128;
                    for (uint32_t fb = flg; fb; fb &= fb - 1) {
                        const int j = __builtin_ctz(fb);
                        const int k = hh * 64 + ccl * 8 + j;
                        float s = 0.0f;
#pragma unroll 4
                        for (int i8 = 0; i8 < 16; ++i8) {
                            const uint4 tb = *reinterpret_cast<const uint4*>(
                                &T[k * 128 + ((i8 ^ (k & 15)) << 3)]);
                            const f32x4 xA = *reinterpret_cast<const f32x4*>(xr + i8 * 8);
                            const f32x4 xB = *reinterpret_cast<const f32x4*>(xr + i8 * 8 + 4);
                            const uint32_t tu[4] = {tb.x, tb.y, tb.z, tb.w};
                            s = __builtin_fmaf(xA[0], __uint_as_float(tu[0] << 16), s);
                            s = __builtin_fmaf(xA[1], __uint_as_float(tu[0] & 0xFFFF0000u), s);
                            s = __builtin_fmaf(xA[2], __uint_as_float(tu[1] << 16), s);
                            s = __builtin_fmaf(xA[3], __uint_as_float(tu[1] & 0xFFFF0000u), s);
                            s = __builtin_fmaf(xB[0], __uint_as_float(tu[2] << 16), s);
                            s = __builtin_fmaf(xB[1], __uint_as_float(tu[2] & 0xFFFF0000u), s);
                            s = __builtin_fmaf(xB[2], __uint_as_float(tu[3] << 16), s);
                            s = __builtin_fmaf(xB[3], __uint_as_float(tu[3] & 0xFFFF0000u), s);
                        }
                        srp = (srp & ~(1u << j)) | ((s > 0.0f) ? (1u << j) : 0u);
                    }
                }
                const uint64_t hhash = (HA * (uint64_t)srp + HB * (uint64_t)ccl + HC0) % PRIME;
                const uint32_t loc   = (uint32_t)hhash % RANGE + (hh ? (uint32_t)ARRAY_SZ : 0u);

                const float f0 = (float)loc;
                float* oi = out_idx + eg * 128 + hh * 64 + ccl * 8;
                *reinterpret_cast<f32x4*>(oi)     = (f32x4){f0, f0 + 1.f, f0 + 2.f, f0 + 3.f};
                *reinterpret_cast<f32x4*>(oi + 4) = (f32x4){f0 + 4.f, f0 + 5.f, f0 + 6.f, f0 + 7.f};

                float wv[8];
#pragma unroll
                for (int j = 0; j < 8; ++j) wv[j] = hw[loc + j];
                if (hh == 0) {
#pragma unroll
                    for (int j = 0; j < 8; ++j) wkeep[m][j] = wv[j];
                } else {
                    float* ov = out_val + eg * 64 + ccl * 8;
                    *reinterpret_cast<f32x4*>(ov) =
                        (f32x4){(wkeep[m][0] + wv[0]) * 0.5f, (wkeep[m][1] + wv[1]) * 0.5f,
                                (wkeep[m][2] + wv[2]) * 0.5f, (wkeep[m][3] + wv[3]) * 0.5f};
                    *reinterpret_cast<f32x4*>(ov + 4) =
                        (f32x4){(wkeep[m][4] + wv[4]) * 0.5f, (wkeep[m][5] + wv[5]) * 0.5f,
                                (wkeep[m][6] + wv[6]) * 0.5f, (wkeep[m][7] + wv[7]) * 0.5f};
                }
            }
        }
    }
}

extern "C" void kernel_launch(void* const* d_in, const int* in_sizes, int n_in,
                              void* d_out, int out_size, void* d_ws, size_t ws_size,
                              hipStream_t stream) {
    const float* x   = (const float*)d_in[0];
    const float* hw  = (const float*)d_in[1];
    const float* lsh = (const float*)d_in[2];
    const void*  rnd = (const void*)d_in[3];

    float* out_idx = (float*)d_out;
    float* out_val = out_idx + (size_t)BATCH * 128;

    lma_mfma7<<<2048, 256, 0, stream>>>(x, hw, lsh, rnd, out_idx, out_val);
}

// Round 17
// 272.749 us; speedup vs baseline: 2.6606x; 1.0235x over previous
//
#include <hip/hip_runtime.h>
#include <stdint.h>

typedef __attribute__((ext_vector_type(8))) short short8;
typedef __attribute__((ext_vector_type(4))) float f32x4;

constexpr int      BATCH    = 524288;
constexpr int      ARRAY_SZ = 262144;
constexpr uint64_t PRIME    = 2038074743ull;
constexpr uint32_t RANGE    = 262137u;          // ARRAY_SZ - 8 + 1
constexpr int      NMT      = BATCH / 16;       // 32768 M-tiles of 16 elements
constexpr int      PSTRIDE  = 68;               // pw row stride: 64 cols + 4 pad
// Sign-certainty bound, 2-split (hi+mid) MFMA vs sequential-fmaf reference:
//   dropped residual <= 2^-16 * Sum|x|          = 1.53e-5 * A
//   MFMA-path roundings <= 264 * 2^-23 * A      = 3.15e-5 * A
//   ref-side roundings  <= 127 * 2^-24 * A      = 0.76e-5 * A
//   total 5.4e-5 * A < EPS = 8e-5 * A. Flagged entries recomputed with the
//   sequential fmaf chain proven bit-exact in rounds 1-16 (absmax 0.0).
constexpr float    EPS      = 8e-5f;

__global__ __launch_bounds__(256, 2)
void lma_mfma8(const float* __restrict__ x,
               const float* __restrict__ hw,
               const float* __restrict__ lsh,
               const void* __restrict__ rnd_raw,
               float* __restrict__ out_idx,   // B*128 floats (idx as f32)
               float* __restrict__ out_val)   // B*64 floats
{
    // T[n][i]: lsh^T as bf16 (exact: {-1,0,1}); 16B-unit XOR swizzle (proven
    // r10/r14/r16). 32768 B.
    __shared__ unsigned short T[128 * 128];
    // pw: per-WAVE transpose buffer for one rep-half (two-pass, r14-proven).
    __shared__ float pw[4][16 * PSTRIDE];            // 17408 B -> total 50176 B

    const int tid  = threadIdx.x;
    const int lane = tid & 63;
    const int wid  = __builtin_amdgcn_readfirstlane(tid >> 6);

    // --- hash constants: detect int64 vs int32 layout of random_numbers ---
    uint64_t HA, HB, HC0;
    {
        const uint64_t first8 = *reinterpret_cast<const uint64_t*>(rnd_raw);
        if (first8 == PRIME) {
            const long long* r64 = reinterpret_cast<const long long*>(rnd_raw);
            HA = (uint64_t)r64[1]; HB = (uint64_t)r64[2]; HC0 = (uint64_t)r64[3];
        } else {
            const int* r32 = reinterpret_cast<const int*>(rnd_raw);
            HA  = (uint64_t)(uint32_t)r32[1];
            HB  = (uint64_t)(uint32_t)r32[2];
            HC0 = (uint64_t)(uint32_t)r32[3];
        }
    }

    // --- stage T = bf16(lsh)^T, XOR-swizzled (one-time) ---
    for (int it = 0; it < 16; ++it) {
        const int flat4 = it * 256 + tid;            // 0..4095
        const int i  = flat4 >> 5;                   // input dim 0..127
        const int n4 = (flat4 & 31) << 2;            // output col base
        const f32x4 v = *reinterpret_cast<const f32x4*>(lsh + i * 128 + n4);
#pragma unroll
        for (int d = 0; d < 4; ++d) {
            const int n = n4 + d;
            T[n * 128 + (((i >> 3) ^ (n & 15)) << 3) + (i & 7)] =
                (unsigned short)(__float_as_uint(v[d]) >> 16);
        }
    }
    __syncthreads();   // only block barrier; T read-only afterwards

    const int r  = lane & 15;         // A/B fragment row (x row, T col)
    const int g  = lane >> 4;         // k-group
    const int e  = lane >> 2;         // phase-2 element (0..15)
    const int c4 = lane & 3;          // phase-2 chunk slot

    // --- prologue: prefetch first tile's x fragment into loop-carried regs ---
    const int mt0 = blockIdx.x * 4 + wid;            // grid 1024 -> stride 4096
    f32x4 xp0, xp1, xp2, xp3, xp4, xp5, xp6, xp7;
    {
        const float* xn = x + (size_t)mt0 * 16 * 128 + r * 128 + g * 8;
        xp0 = *reinterpret_cast<const f32x4*>(xn);
        xp1 = *reinterpret_cast<const f32x4*>(xn + 4);
        xp2 = *reinterpret_cast<const f32x4*>(xn + 32);
        xp3 = *reinterpret_cast<const f32x4*>(xn + 36);
        xp4 = *reinterpret_cast<const f32x4*>(xn + 64);
        xp5 = *reinterpret_cast<const f32x4*>(xn + 68);
        xp6 = *reinterpret_cast<const f32x4*>(xn + 96);
        xp7 = *reinterpret_cast<const f32x4*>(xn + 100);
    }

    // loop-carried pipeline state: pending gathers of previous tile
    float    wv[4][8];            // statically indexed everywhere (SROA)
    size_t   egP = 0;
    int      c4P0 = 0;            // (constant per lane, but keep simple)

#pragma unroll 1
    for (int mt = mt0; mt < NMT; mt += 4096) {
        const int Mb = mt * 16;

        f32x4 acc[8];
#pragma unroll
        for (int n8 = 0; n8 < 8; ++n8) acc[n8] = (f32x4)(0.0f);
        float asum = 0.0f;

        // ---- phase 1: exact 2-way split MFMA; x from loop-carried regs.
        //      xp(t) is OLDER in the vmem FIFO than gathers(t-1), so the
        //      compiler's counted vmcnt waits leave the gathers in flight. ----
#pragma unroll
        for (int ks = 0; ks < 4; ++ks) {
            const f32x4 xa = (ks == 0) ? xp0 : (ks == 1) ? xp2 : (ks == 2) ? xp4 : xp6;
            const f32x4 xc = (ks == 0) ? xp1 : (ks == 1) ? xp3 : (ks == 2) ? xp5 : xp7;
            float xs[8] = {xa[0], xa[1], xa[2], xa[3], xc[0], xc[1], xc[2], xc[3]};
#pragma unroll
            for (int j = 0; j < 8; ++j) asum += fabsf(xs[j]);

            union { uint32_t u[4]; short8 v; } Ahi, Ami;
#pragma unroll
            for (int p = 0; p < 4; ++p) {
                const uint32_t b0 = __float_as_uint(xs[2 * p]);
                const uint32_t b1 = __float_as_uint(xs[2 * p + 1]);
                const uint32_t h0 = b0 & 0xFFFF0000u, h1 = b1 & 0xFFFF0000u;
                const float    t0 = xs[2 * p] - __uint_as_float(h0);
                const float    t1 = xs[2 * p + 1] - __uint_as_float(h1);
                const uint32_t m0 = __float_as_uint(t0) & 0xFFFF0000u;
                const uint32_t m1 = __float_as_uint(t1) & 0xFFFF0000u;
                Ahi.u[p] = h1 | (h0 >> 16);
                Ami.u[p] = m1 | (m0 >> 16);
            }
#pragma unroll
            for (int n8 = 0; n8 < 8; ++n8) {
                const short8 bf = *reinterpret_cast<const short8*>(
                    &T[(n8 * 16 + r) * 128 + (((ks * 4 + g) ^ r) << 3)]);
                acc[n8] = __builtin_amdgcn_mfma_f32_16x16x32_bf16(Ahi.v, bf, acc[n8], 0, 0, 0);
                acc[n8] = __builtin_amdgcn_mfma_f32_16x16x32_bf16(Ami.v, bf, acc[n8], 0, 0, 0);
            }
        }

        // ---- prefetch next tile's x NOW (older than this tile's gathers) ----
        {
            const int mtn = (mt + 4096 < NMT) ? mt + 4096 : mt;
            const float* xn = x + (size_t)mtn * 16 * 128 + r * 128 + g * 8;
            xp0 = *reinterpret_cast<const f32x4*>(xn);
            xp1 = *reinterpret_cast<const f32x4*>(xn + 4);
            xp2 = *reinterpret_cast<const f32x4*>(xn + 32);
            xp3 = *reinterpret_cast<const f32x4*>(xn + 36);
            xp4 = *reinterpret_cast<const f32x4*>(xn + 64);
            xp5 = *reinterpret_cast<const f32x4*>(xn + 68);
            xp6 = *reinterpret_cast<const f32x4*>(xn + 96);
            xp7 = *reinterpret_cast<const f32x4*>(xn + 100);
        }

        // row-|x| sums over k-groups; each lane picks its element's bound
        asum += __shfl_xor(asum, 16);
        asum += __shfl_xor(asum, 32);
        const float bnd = __shfl(asum, e) * EPS;

        const size_t eg = (size_t)(Mb + e);
        uint32_t locN[4];

        // ---- phase 2 per rep-half: wave-private transpose; compute loc,
        //      store out_idx; gathers are NOT consumed here ----
#pragma unroll
        for (int hh = 0; hh < 2; ++hh) {
#pragma unroll
            for (int n8h = 0; n8h < 4; ++n8h)
#pragma unroll
                for (int reg = 0; reg < 4; ++reg)
                    pw[wid][(g * 4 + reg) * PSTRIDE + n8h * 16 + r] =
                        acc[hh * 4 + n8h][reg];
            asm volatile("s_waitcnt lgkmcnt(0)" ::: "memory");

#pragma unroll
            for (int m = 0; m < 2; ++m) {
                const int ccl = c4 + 4 * m;          // chunk id within rep
                const f32x4 pa = *reinterpret_cast<const f32x4*>(
                    &pw[wid][e * PSTRIDE + ccl * 8]);
                const f32x4 pb = *reinterpret_cast<const f32x4*>(
                    &pw[wid][e * PSTRIDE + ccl * 8 + 4]);
                const float p[8] = {pa[0], pa[1], pa[2], pa[3],
                                    pb[0], pb[1], pb[2], pb[3]};
                uint32_t srp = 0, flg = 0;
#pragma unroll
                for (int j = 0; j < 8; ++j) {
                    srp |= (p[j] > 0.0f) ? (1u << j) : 0u;
                    flg |= (fabsf(p[j]) <= bnd) ? (1u << j) : 0u;
                }
                if (flg) {  // rare exact fallback: sequential fmaf, i = 0..127
                    const float* xr = x + eg * 128;
                    for (uint32_t fb = flg; fb; fb &= fb - 1) {
                        const int j = __builtin_ctz(fb);
                        const int k = hh * 64 + ccl * 8 + j;
                        float s = 0.0f;
#pragma unroll 4
                        for (int i8 = 0; i8 < 16; ++i8) {
                            const uint4 tb = *reinterpret_cast<const uint4*>(
                                &T[k * 128 + ((i8 ^ (k & 15)) << 3)]);
                            const f32x4 xA = *reinterpret_cast<const f32x4*>(xr + i8 * 8);
                            const f32x4 xB = *reinterpret_cast<const f32x4*>(xr + i8 * 8 + 4);
                            const uint32_t tu[4] = {tb.x, tb.y, tb.z, tb.w};
                            s = __builtin_fmaf(xA[0], __uint_as_float(tu[0] << 16), s);
                            s = __builtin_fmaf(xA[1], __uint_as_float(tu[0] & 0xFFFF0000u), s);
                            s = __builtin_fmaf(xA[2], __uint_as_float(tu[1] << 16), s);
                            s = __builtin_fmaf(xA[3], __uint_as_float(tu[1] & 0xFFFF0000u), s);
                            s = __builtin_fmaf(xB[0], __uint_as_float(tu[2] << 16), s);
                            s = __builtin_fmaf(xB[1], __uint_as_float(tu[2] & 0xFFFF0000u), s);
                            s = __builtin_fmaf(xB[2], __uint_as_float(tu[3] << 16), s);
                            s = __builtin_fmaf(xB[3], __uint_as_float(tu[3] & 0xFFFF0000u), s);
                        }
                        srp = (srp & ~(1u << j)) | ((s > 0.0f) ? (1u << j) : 0u);
                    }
                }
                const uint64_t hhash = (HA * (uint64_t)srp + HB * (uint64_t)ccl + HC0) % PRIME;
                const uint32_t loc   = (uint32_t)hhash % RANGE + (hh ? (uint32_t)ARRAY_SZ : 0u);
                locN[hh * 2 + m] = loc;

                const float f0 = (float)loc;
                float* oi = out_idx + eg * 128 + hh * 64 + ccl * 8;
                *reinterpret_cast<f32x4*>(oi)     = (f32x4){f0, f0 + 1.f, f0 + 2.f, f0 + 3.f};
                *reinterpret_cast<f32x4*>(oi + 4) = (f32x4){f0 + 4.f, f0 + 5.f, f0 + 6.f, f0 + 7.f};
            }
        }

        // ---- consume PREVIOUS tile's gathers (had a whole tile to land) ----
        if (mt != mt0) {
#pragma unroll
            for (int m = 0; m < 2; ++m) {
                const int ccl = c4 + 4 * m;
                float* ov = out_val + egP * 64 + ccl * 8;
                *reinterpret_cast<f32x4*>(ov) =
                    (f32x4){(wv[m][0] + wv[2 + m][0]) * 0.5f, (wv[m][1] + wv[2 + m][1]) * 0.5f,
                            (wv[m][2] + wv[2 + m][2]) * 0.5f, (wv[m][3] + wv[2 + m][3]) * 0.5f};
                *reinterpret_cast<f32x4*>(ov + 4) =
                    (f32x4){(wv[m][4] + wv[2 + m][4]) * 0.5f, (wv[m][5] + wv[2 + m][5]) * 0.5f,
                            (wv[m][6] + wv[2 + m][6]) * 0.5f, (wv[m][7] + wv[2 + m][7]) * 0.5f};
            }
        }

        // ---- issue THIS tile's gathers; consumed next iteration ----
#pragma unroll
        for (int task = 0; task < 4; ++task)
#pragma unroll
            for (int j = 0; j < 8; ++j)
                wv[task][j] = hw[locN[task] + j];

        egP = eg;
    }

    // ---- epilogue: consume the final tile's gathers ----
#pragma unroll
    for (int m = 0; m < 2; ++m) {
        const int ccl = c4 + 4 * m;
        float* ov = out_val + egP * 64 + ccl * 8;
        *reinterpret_cast<f32x4*>(ov) =
            (f32x4){(wv[m][0] + wv[2 + m][0]) * 0.5f, (wv[m][1] + wv[2 + m][1]) * 0.5f,
                    (wv[m][2] + wv[2 + m][2]) * 0.5f, (wv[m][3] + wv[2 + m][3]) * 0.5f};
        *reinterpret_cast<f32x4*>(ov + 4) =
            (f32x4){(wv[m][4] + wv[2 + m][4]) * 0.5f, (wv[m][5] + wv[2 + m][5]) * 0.5f,
                    (wv[m][6] + wv[2 + m][6]) * 0.5f, (wv[m][7] + wv[2 + m][7]) * 0.5f};
    }
}

extern "C" void kernel_launch(void* const* d_in, const int* in_sizes, int n_in,
                              void* d_out, int out_size, void* d_ws, size_t ws_size,
                              hipStream_t stream) {
    const float* x   = (const float*)d_in[0];
    const float* hw  = (const float*)d_in[1];
    const float* lsh = (const float*)d_in[2];
    const void*  rnd = (const void*)d_in[3];

    float* out_idx = (float*)d_out;
    float* out_val = out_idx + (size_t)BATCH * 128;

    lma_mfma8<<<1024, 256, 0, stream>>>(x, hw, lsh, rnd, out_idx, out_val);
}